// Round 1
// baseline (1654.363 us; speedup 1.0000x reference)
//
#include <hip/hip_runtime.h>
#include <math.h>

// Markowitz min-variance via FISTA, one block (512 thr, 8 waves) per problem.
// Q register-resident: thread (r4=tid&63, e=tid>>6) owns Q[4*r4..+3][32*e..+31].
// Wave 0 owns the FISTA scalar state + projection (shuffle-only Newton root-find).

#define NA    256
#define CAPW  0.05f

__device__ __forceinline__ float wsum(float v) {
    #pragma unroll
    for (int m = 32; m >= 1; m >>= 1) v += __shfl_xor(v, m, 64);
    return v;
}
__device__ __forceinline__ float wmin(float v) {
    #pragma unroll
    for (int m = 32; m >= 1; m >>= 1) v = fminf(v, __shfl_xor(v, m, 64));
    return v;
}
__device__ __forceinline__ float wmax(float v) {
    #pragma unroll
    for (int m = 32; m >= 1; m >>= 1) v = fmaxf(v, __shfl_xor(v, m, 64));
    return v;
}

__global__ void __launch_bounds__(512, 2)
markowitz_fista(const float* __restrict__ A, float* __restrict__ out)
{
    __shared__ float A_lds[32 * 256];   // 32 KB A staging (build phase only)
    __shared__ float y_lds[256];        // published y / u vector
    __shared__ float g_lds[256];        // Q*y result
    __shared__ float p_lds[8 * 256];    // matvec partials, [e][r] layout (conflict-free)

    const int tid = threadIdx.x;
    const int b   = blockIdx.x;
    const int r4  = tid & 63;
    const int e   = tid >> 6;           // wave id == col-chunk
    const int R0  = r4 * 4;
    const int C0  = e * 32;

    const float* __restrict__ Ab = A + (size_t)b * NA * NA;

    // ---------------- Phase 1: Q = A^T A into registers ----------------
    float q[4][32];
    #pragma unroll
    for (int a = 0; a < 4; ++a)
        #pragma unroll
        for (int k = 0; k < 32; ++k) q[a][k] = 0.0f;

    for (int it = 0; it < 8; ++it) {
        __syncthreads();
        const float4* src = (const float4*)(Ab + it * 32 * 256);
        float4* dst = (float4*)A_lds;
        #pragma unroll
        for (int qd = 0; qd < 4; ++qd) dst[qd * 512 + tid] = src[qd * 512 + tid];
        __syncthreads();
        for (int ii = 0; ii < 32; ++ii) {
            const float* row = A_lds + ii * 256;
            float4 rv = *(const float4*)(row + R0);      // lanes contiguous: conflict-free
            #pragma unroll
            for (int cc = 0; cc < 8; ++cc) {
                float4 cv = *(const float4*)(row + C0 + 4 * cc);  // wave-uniform broadcast
                q[0][4*cc+0] += rv.x * cv.x;  q[0][4*cc+1] += rv.x * cv.y;
                q[0][4*cc+2] += rv.x * cv.z;  q[0][4*cc+3] += rv.x * cv.w;
                q[1][4*cc+0] += rv.y * cv.x;  q[1][4*cc+1] += rv.y * cv.y;
                q[1][4*cc+2] += rv.y * cv.z;  q[1][4*cc+3] += rv.y * cv.w;
                q[2][4*cc+0] += rv.z * cv.x;  q[2][4*cc+1] += rv.z * cv.y;
                q[2][4*cc+2] += rv.z * cv.z;  q[2][4*cc+3] += rv.z * cv.w;
                q[3][4*cc+0] += rv.w * cv.x;  q[3][4*cc+1] += rv.w * cv.y;
                q[3][4*cc+2] += rv.w * cv.z;  q[3][4*cc+3] += rv.w * cv.w;
            }
        }
    }

    // g_lds = Q * y_lds.  Opens with a barrier (orders wave0's y publish), ends
    // with a barrier (g visible to wave0).
    auto matvec = [&]() {
        __syncthreads();
        float a0 = 0.f, a1 = 0.f, a2 = 0.f, a3 = 0.f;
        const float* yv = y_lds + C0;
        #pragma unroll
        for (int cc = 0; cc < 8; ++cc) {
            float4 y4 = *(const float4*)(yv + 4 * cc);
            float ys[4] = {y4.x, y4.y, y4.z, y4.w};
            #pragma unroll
            for (int d = 0; d < 4; ++d) {
                a0 += q[0][4*cc+d] * ys[d];
                a1 += q[1][4*cc+d] * ys[d];
                a2 += q[2][4*cc+d] * ys[d];
                a3 += q[3][4*cc+d] * ys[d];
            }
        }
        *(float4*)(p_lds + e * 256 + R0) = make_float4(a0, a1, a2, a3);
        __syncthreads();
        if (tid < 256) {
            float s = 0.0f;
            #pragma unroll
            for (int ee = 0; ee < 8; ++ee) s += p_lds[ee * 256 + tid];
            g_lds[tid] = s;
        }
        __syncthreads();
    };

    // ---------------- Phase 2: power iteration for step size ----------------
    if (tid < 256) y_lds[tid] = 0.0625f;   // u0 = 1/sqrt(256)

    float u0 = 0.f, u1 = 0.f, u2 = 0.f, u3 = 0.f;
    for (int p = 0; p < 30; ++p) {
        matvec();
        if (tid < 64) {
            float4 g4 = *(const float4*)(g_lds + 4 * tid);
            float ss = wsum(g4.x*g4.x + g4.y*g4.y + g4.z*g4.z + g4.w*g4.w);
            float inv = 1.0f / (sqrtf(ss) + 1e-12f);
            u0 = g4.x * inv; u1 = g4.y * inv; u2 = g4.z * inv; u3 = g4.w * inv;
            *(float4*)(y_lds + 4 * tid) = make_float4(u0, u1, u2, u3);
        }
    }
    matvec();  // Q*u for Rayleigh quotient

    float step2 = 0.f, t = 1.0f;
    float wa = 0.f, wb = 0.f, wc = 0.f, wd = 0.f;
    float ya = 0.f, yb = 0.f, yc = 0.f, yd = 0.f;
    if (tid < 64) {
        float4 g4 = *(const float4*)(g_lds + 4 * tid);
        float lm = wsum(u0*g4.x + u1*g4.y + u2*g4.z + u3*g4.w);
        float step = 1.0f / (2.0f * lm + 1e-12f);
        step2 = 2.0f * step;                         // v = y - step*(2*Q*y)
        // w0 = project(uniform 1/256) = 1/256 exactly (tau = 0)
        wa = wb = wc = wd = 1.0f / 256.0f;
        ya = yb = yc = yd = 1.0f / 256.0f;
        *(float4*)(y_lds + 4 * tid) = make_float4(ya, yb, yc, yd);
    }

    // ---------------- Phase 3: FISTA ----------------
    for (int itn = 0; itn < 300; ++itn) {
        matvec();
        if (tid < 64) {
            float4 g4 = *(const float4*)(g_lds + 4 * tid);
            float v0 = ya - step2 * g4.x;
            float v1 = yb - step2 * g4.y;
            float v2 = yc - step2 * g4.z;
            float v3 = yd - step2 * g4.w;

            // safeguarded Newton root-find for s(tau) = sum(clip(v-tau)) = 1
            float lo = wmin(fminf(fminf(v0, v1), fminf(v2, v3))) - CAPW;
            float hi = wmax(fmaxf(fmaxf(v0, v1), fmaxf(v2, v3))) + CAPW;
            float tau = 0.5f * (lo + hi);
            for (int ni = 0; ni < 40; ++ni) {
                float z0 = v0 - tau, z1 = v1 - tau, z2 = v2 - tau, z3 = v3 - tau;
                float c0 = fminf(fmaxf(z0, -CAPW), CAPW);
                float c1 = fminf(fmaxf(z1, -CAPW), CAPW);
                float c2 = fminf(fmaxf(z2, -CAPW), CAPW);
                float c3 = fminf(fmaxf(z3, -CAPW), CAPW);
                float s   = wsum(c0 + c1 + c2 + c3);
                float cnt = wsum((fabsf(z0) < CAPW ? 1.f : 0.f) +
                                 (fabsf(z1) < CAPW ? 1.f : 0.f) +
                                 (fabsf(z2) < CAPW ? 1.f : 0.f) +
                                 (fabsf(z3) < CAPW ? 1.f : 0.f));
                float sm1 = s - 1.0f;
                if (fabsf(sm1) <= 1e-5f) break;        // wave-uniform
                if (sm1 > 0.0f) lo = tau; else hi = tau;
                float tn2 = tau + sm1 / fmaxf(cnt, 1.0f);   // Newton (s' = -n_int)
                if (!(tn2 > lo && tn2 < hi)) tn2 = 0.5f * (lo + hi);  // bisect fallback
                tau = tn2;
                if (hi - lo <= 1e-9f) break;
            }
            // exact tau from the active set (identical formula to the reference)
            float z0 = v0 - tau, z1 = v1 - tau, z2 = v2 - tau, z3 = v3 - tau;
            float i0 = (fabsf(z0) < CAPW) ? 1.f : 0.f;
            float i1 = (fabsf(z1) < CAPW) ? 1.f : 0.f;
            float i2 = (fabsf(z2) < CAPW) ? 1.f : 0.f;
            float i3 = (fabsf(z3) < CAPW) ? 1.f : 0.f;
            float sv  = wsum(i0*v0 + i1*v1 + i2*v2 + i3*v3);
            float nin = wsum(i0 + i1 + i2 + i3);
            float kdf = wsum(((z0 >=  CAPW ? 1.f : 0.f) - (z0 <= -CAPW ? 1.f : 0.f)) +
                             ((z1 >=  CAPW ? 1.f : 0.f) - (z1 <= -CAPW ? 1.f : 0.f)) +
                             ((z2 >=  CAPW ? 1.f : 0.f) - (z2 <= -CAPW ? 1.f : 0.f)) +
                             ((z3 >=  CAPW ? 1.f : 0.f) - (z3 <= -CAPW ? 1.f : 0.f)));
            float tauf = (sv + CAPW * kdf - 1.0f) / fmaxf(nin, 1.0f);
            float w0n = fminf(fmaxf(v0 - tauf, -CAPW), CAPW);
            float w1n = fminf(fmaxf(v1 - tauf, -CAPW), CAPW);
            float w2n = fminf(fmaxf(v2 - tauf, -CAPW), CAPW);
            float w3n = fminf(fmaxf(v3 - tauf, -CAPW), CAPW);

            // FISTA momentum update
            float tn = 0.5f * (1.0f + sqrtf(1.0f + 4.0f * t * t));
            float beta = (t - 1.0f) / tn;
            float y0n = w0n + beta * (w0n - wa);
            float y1n = w1n + beta * (w1n - wb);
            float y2n = w2n + beta * (w2n - wc);
            float y3n = w3n + beta * (w3n - wd);
            wa = w0n; wb = w1n; wc = w2n; wd = w3n;
            ya = y0n; yb = y1n; yc = y2n; yd = y3n;
            t = tn;
            *(float4*)(y_lds + 4 * tid) = make_float4(ya, yb, yc, yd);
        }
    }

    if (tid < 64) {
        *(float4*)(out + b * 256 + 4 * tid) = make_float4(wa, wb, wc, wd);
    }
}

extern "C" void kernel_launch(void* const* d_in, const int* in_sizes, int n_in,
                              void* d_out, int out_size, void* d_ws, size_t ws_size,
                              hipStream_t stream) {
    (void)in_sizes; (void)n_in; (void)d_ws; (void)ws_size; (void)out_size;
    const float* A = (const float*)d_in[0];
    float* out = (float*)d_out;
    hipLaunchKernelGGL(markowitz_fista, dim3(512), dim3(512), 0, stream, A, out);
}

// Round 2
// 1182.489 us; speedup vs baseline: 1.3991x; 1.3991x over previous
//
#include <hip/hip_runtime.h>
#include <math.h>

// Markowitz min-variance via FISTA, one block (512 thr, 8 waves) per problem.
// Q register-resident: thread (r4=tid&63, e=tid>>6) owns Q[4*r4..+3][32*e..+31].
// Wave 0 owns FISTA state + projection. R2: DPP reductions (no ds_swizzle),
// tau warm-start across iterations, wave0-only partial reduce (2 barriers/iter).

#define NA    256
#define CAPW  0.05f

// ---- DPP wave-64 reductions (rocPRIM-style row_shr + row_bcast chain) ----
template<int CTRL, int RM>
__device__ __forceinline__ float dpp0(float x) {      // old = 0, bound_ctrl = true
    return __int_as_float(__builtin_amdgcn_update_dpp(
        0, __float_as_int(x), CTRL, RM, 0xf, true));
}
template<int CTRL, int RM>
__device__ __forceinline__ float dppI(float x, float ident) { // old = ident
    return __int_as_float(__builtin_amdgcn_update_dpp(
        __float_as_int(ident), __float_as_int(x), CTRL, RM, 0xf, false));
}
__device__ __forceinline__ float bcast63(float x) {
    return __int_as_float(__builtin_amdgcn_readlane(__float_as_int(x), 63));
}
__device__ __forceinline__ float wsum(float x) {
    x += dpp0<0x111, 0xf>(x);   // row_shr:1
    x += dpp0<0x112, 0xf>(x);   // row_shr:2
    x += dpp0<0x114, 0xf>(x);   // row_shr:4
    x += dpp0<0x118, 0xf>(x);   // row_shr:8
    x += dpp0<0x142, 0xa>(x);   // row_bcast:15 -> rows 1,3
    x += dpp0<0x143, 0xc>(x);   // row_bcast:31 -> rows 2,3
    return bcast63(x);
}
__device__ __forceinline__ float wmin(float x) {
    const float I = 1e30f;
    x = fminf(x, dppI<0x111, 0xf>(x, I));
    x = fminf(x, dppI<0x112, 0xf>(x, I));
    x = fminf(x, dppI<0x114, 0xf>(x, I));
    x = fminf(x, dppI<0x118, 0xf>(x, I));
    x = fminf(x, dppI<0x142, 0xa>(x, I));
    x = fminf(x, dppI<0x143, 0xc>(x, I));
    return bcast63(x);
}
__device__ __forceinline__ float wmax(float x) {
    const float I = -1e30f;
    x = fmaxf(x, dppI<0x111, 0xf>(x, I));
    x = fmaxf(x, dppI<0x112, 0xf>(x, I));
    x = fmaxf(x, dppI<0x114, 0xf>(x, I));
    x = fmaxf(x, dppI<0x118, 0xf>(x, I));
    x = fmaxf(x, dppI<0x142, 0xa>(x, I));
    x = fmaxf(x, dppI<0x143, 0xc>(x, I));
    return bcast63(x);
}

__global__ void __launch_bounds__(512, 2)
markowitz_fista(const float* __restrict__ A, float* __restrict__ out)
{
    __shared__ float A_lds[32 * 256];   // build-phase A staging (32 KB)
    __shared__ float y_lds[256];        // published y / u vector
    __shared__ float p_lds[8 * 256];    // matvec partials, [e][r] layout

    const int tid = threadIdx.x;
    const int b   = blockIdx.x;
    const int r4  = tid & 63;
    const int e   = tid >> 6;           // wave id == col-chunk
    const int R0  = r4 * 4;
    const int C0  = e * 32;

    const float* __restrict__ Ab = A + (size_t)b * NA * NA;

    // ---------------- Phase 1: Q = A^T A into registers ----------------
    float q[4][32];
    #pragma unroll
    for (int a = 0; a < 4; ++a)
        #pragma unroll
        for (int k = 0; k < 32; ++k) q[a][k] = 0.0f;

    for (int it = 0; it < 8; ++it) {
        __syncthreads();
        const float4* src = (const float4*)(Ab + it * 32 * 256);
        float4* dst = (float4*)A_lds;
        #pragma unroll
        for (int qd = 0; qd < 4; ++qd) dst[qd * 512 + tid] = src[qd * 512 + tid];
        __syncthreads();
        for (int ii = 0; ii < 32; ++ii) {
            const float* row = A_lds + ii * 256;
            float4 rv = *(const float4*)(row + R0);
            #pragma unroll
            for (int cc = 0; cc < 8; ++cc) {
                float4 cv = *(const float4*)(row + C0 + 4 * cc);
                q[0][4*cc+0] += rv.x * cv.x;  q[0][4*cc+1] += rv.x * cv.y;
                q[0][4*cc+2] += rv.x * cv.z;  q[0][4*cc+3] += rv.x * cv.w;
                q[1][4*cc+0] += rv.y * cv.x;  q[1][4*cc+1] += rv.y * cv.y;
                q[1][4*cc+2] += rv.y * cv.z;  q[1][4*cc+3] += rv.y * cv.w;
                q[2][4*cc+0] += rv.z * cv.x;  q[2][4*cc+1] += rv.z * cv.y;
                q[2][4*cc+2] += rv.z * cv.z;  q[2][4*cc+3] += rv.z * cv.w;
                q[3][4*cc+0] += rv.w * cv.x;  q[3][4*cc+1] += rv.w * cv.y;
                q[3][4*cc+2] += rv.w * cv.z;  q[3][4*cc+3] += rv.w * cv.w;
            }
        }
    }

    // all waves: compute partials of Q*y_lds into p_lds (B1 ... B2)
    auto partials = [&]() {
        __syncthreads();                               // B1: y_lds visible
        float a0 = 0.f, a1 = 0.f, a2 = 0.f, a3 = 0.f;
        const float* yv = y_lds + C0;
        #pragma unroll
        for (int cc = 0; cc < 8; ++cc) {
            float4 y4 = *(const float4*)(yv + 4 * cc);
            a0 += q[0][4*cc+0]*y4.x + q[0][4*cc+1]*y4.y + q[0][4*cc+2]*y4.z + q[0][4*cc+3]*y4.w;
            a1 += q[1][4*cc+0]*y4.x + q[1][4*cc+1]*y4.y + q[1][4*cc+2]*y4.z + q[1][4*cc+3]*y4.w;
            a2 += q[2][4*cc+0]*y4.x + q[2][4*cc+1]*y4.y + q[2][4*cc+2]*y4.z + q[2][4*cc+3]*y4.w;
            a3 += q[3][4*cc+0]*y4.x + q[3][4*cc+1]*y4.y + q[3][4*cc+2]*y4.z + q[3][4*cc+3]*y4.w;
        }
        *(float4*)(p_lds + e * 256 + R0) = make_float4(a0, a1, a2, a3);
        __syncthreads();                               // B2: p_lds visible
    };
    // wave0 (tid<64): reduce the 8 partials for rows 4*tid..4*tid+3
    auto reduceg = [&]() -> float4 {
        float4 r = *(const float4*)(p_lds + 4 * tid);
        #pragma unroll
        for (int ee = 1; ee < 8; ++ee) {
            float4 pv = *(const float4*)(p_lds + ee * 256 + 4 * tid);
            r.x += pv.x; r.y += pv.y; r.z += pv.z; r.w += pv.w;
        }
        return r;
    };

    // ---------------- Phase 2: power iteration for step size ----------------
    if (tid < 64) {
        *(float4*)(y_lds + 4 * tid) = make_float4(0.0625f, 0.0625f, 0.0625f, 0.0625f);
    }
    float u0 = 0.f, u1 = 0.f, u2 = 0.f, u3 = 0.f;
    for (int p = 0; p < 30; ++p) {
        partials();
        if (tid < 64) {
            float4 g4 = reduceg();
            float ss = wsum(g4.x*g4.x + g4.y*g4.y + g4.z*g4.z + g4.w*g4.w);
            float inv = 1.0f / (sqrtf(ss) + 1e-12f);
            u0 = g4.x * inv; u1 = g4.y * inv; u2 = g4.z * inv; u3 = g4.w * inv;
            *(float4*)(y_lds + 4 * tid) = make_float4(u0, u1, u2, u3);
        }
    }
    partials();   // Q*u for Rayleigh quotient

    float step2 = 0.f, t = 1.0f, tau_ws = 0.0f;
    float wa = 0.f, wb = 0.f, wc = 0.f, wd = 0.f;
    float ya = 0.f, yb = 0.f, yc = 0.f, yd = 0.f;
    if (tid < 64) {
        float4 g4 = reduceg();
        float lm = wsum(u0*g4.x + u1*g4.y + u2*g4.z + u3*g4.w);
        float step = 1.0f / (2.0f * lm + 1e-12f);
        step2 = 2.0f * step;
        wa = wb = wc = wd = 1.0f / 256.0f;    // project(uniform) = uniform (tau=0)
        ya = yb = yc = yd = 1.0f / 256.0f;
        *(float4*)(y_lds + 4 * tid) = make_float4(ya, yb, yc, yd);
    }

    // ---------------- Phase 3: FISTA ----------------
    for (int itn = 0; itn < 300; ++itn) {
        partials();
        if (tid < 64) {
            float4 g4 = reduceg();
            float v0 = ya - step2 * g4.x;
            float v1 = yb - step2 * g4.y;
            float v2 = yc - step2 * g4.z;
            float v3 = yd - step2 * g4.w;

            float lo = wmin(fminf(fminf(v0, v1), fminf(v2, v3))) - CAPW;
            float hi = wmax(fmaxf(fmaxf(v0, v1), fmaxf(v2, v3))) + CAPW;
            // warm-start from previous iteration's exact tau, clamped into bracket
            float tau = fminf(fmaxf(tau_ws, lo), hi);
            for (int ni = 0; ni < 40; ++ni) {
                float z0 = v0 - tau, z1 = v1 - tau, z2 = v2 - tau, z3 = v3 - tau;
                float c0 = fminf(fmaxf(z0, -CAPW), CAPW);
                float c1 = fminf(fmaxf(z1, -CAPW), CAPW);
                float c2 = fminf(fmaxf(z2, -CAPW), CAPW);
                float c3 = fminf(fmaxf(z3, -CAPW), CAPW);
                float s   = wsum(c0 + c1 + c2 + c3);
                float cnt = wsum((fabsf(z0) < CAPW ? 1.f : 0.f) +
                                 (fabsf(z1) < CAPW ? 1.f : 0.f) +
                                 (fabsf(z2) < CAPW ? 1.f : 0.f) +
                                 (fabsf(z3) < CAPW ? 1.f : 0.f));
                float sm1 = s - 1.0f;
                if (fabsf(sm1) <= 1e-6f) break;         // wave-uniform (sgpr)
                if (sm1 > 0.0f) lo = tau; else hi = tau;
                float tn2 = tau + sm1 / fmaxf(cnt, 1.0f);   // Newton: s' = -n_interior
                if (!(tn2 > lo && tn2 < hi)) tn2 = 0.5f * (lo + hi);
                tau = tn2;
                if (hi - lo <= 1e-9f) break;
            }
            // exact tau from active set (same formula as reference)
            float z0 = v0 - tau, z1 = v1 - tau, z2 = v2 - tau, z3 = v3 - tau;
            float i0 = (fabsf(z0) < CAPW) ? 1.f : 0.f;
            float i1 = (fabsf(z1) < CAPW) ? 1.f : 0.f;
            float i2 = (fabsf(z2) < CAPW) ? 1.f : 0.f;
            float i3 = (fabsf(z3) < CAPW) ? 1.f : 0.f;
            float sv  = wsum(i0*v0 + i1*v1 + i2*v2 + i3*v3);
            float nin = wsum(i0 + i1 + i2 + i3);
            float kdf = wsum(((z0 >=  CAPW ? 1.f : 0.f) - (z0 <= -CAPW ? 1.f : 0.f)) +
                             ((z1 >=  CAPW ? 1.f : 0.f) - (z1 <= -CAPW ? 1.f : 0.f)) +
                             ((z2 >=  CAPW ? 1.f : 0.f) - (z2 <= -CAPW ? 1.f : 0.f)) +
                             ((z3 >=  CAPW ? 1.f : 0.f) - (z3 <= -CAPW ? 1.f : 0.f)));
            float tauf = (sv + CAPW * kdf - 1.0f) / fmaxf(nin, 1.0f);
            tau_ws = tauf;
            float w0n = fminf(fmaxf(v0 - tauf, -CAPW), CAPW);
            float w1n = fminf(fmaxf(v1 - tauf, -CAPW), CAPW);
            float w2n = fminf(fmaxf(v2 - tauf, -CAPW), CAPW);
            float w3n = fminf(fmaxf(v3 - tauf, -CAPW), CAPW);

            float tn = 0.5f * (1.0f + sqrtf(1.0f + 4.0f * t * t));
            float beta = (t - 1.0f) / tn;
            float y0n = w0n + beta * (w0n - wa);
            float y1n = w1n + beta * (w1n - wb);
            float y2n = w2n + beta * (w2n - wc);
            float y3n = w3n + beta * (w3n - wd);
            wa = w0n; wb = w1n; wc = w2n; wd = w3n;
            ya = y0n; yb = y1n; yc = y2n; yd = y3n;
            t = tn;
            *(float4*)(y_lds + 4 * tid) = make_float4(ya, yb, yc, yd);
        }
    }

    if (tid < 64) {
        *(float4*)(out + b * 256 + 4 * tid) = make_float4(wa, wb, wc, wd);
    }
}

extern "C" void kernel_launch(void* const* d_in, const int* in_sizes, int n_in,
                              void* d_out, int out_size, void* d_ws, size_t ws_size,
                              hipStream_t stream) {
    (void)in_sizes; (void)n_in; (void)d_ws; (void)ws_size; (void)out_size;
    const float* A = (const float*)d_in[0];
    float* out = (float*)d_out;
    hipLaunchKernelGGL(markowitz_fista, dim3(512), dim3(512), 0, stream, A, out);
}

// Round 3
// 1057.827 us; speedup vs baseline: 1.5639x; 1.1178x over previous
//
#include <hip/hip_runtime.h>
#include <math.h>

// Markowitz min-variance via FISTA, one block (512 thr, 8 waves) per problem.
// Q register-resident: thread (r4=tid&63, e=tid>>6) owns Q[4*r4..+3][32*e..+31].
// R3: fp32 packed math (v_pk_fma_f32), Newton tolerance 1e-5 (1e-6 was fp32
// noise -> bisection spin), exact-tau folded into last Newton eval
// (tau_exact = tau + (s-1)/n_int, algebraically identical to the reference's
// active-set formula), frozen-w early exit.

#define NA    256
#define CAPW  0.05f

typedef float v2f __attribute__((ext_vector_type(2)));

// ---- DPP wave-64 reductions ----
template<int CTRL, int RM>
__device__ __forceinline__ float dpp0(float x) {      // old = 0, bound_ctrl = true
    return __int_as_float(__builtin_amdgcn_update_dpp(
        0, __float_as_int(x), CTRL, RM, 0xf, true));
}
template<int CTRL, int RM>
__device__ __forceinline__ float dppI(float x, float ident) { // old = ident
    return __int_as_float(__builtin_amdgcn_update_dpp(
        __float_as_int(ident), __float_as_int(x), CTRL, RM, 0xf, false));
}
__device__ __forceinline__ float bcast63(float x) {
    return __int_as_float(__builtin_amdgcn_readlane(__float_as_int(x), 63));
}
__device__ __forceinline__ float wsum(float x) {
    x += dpp0<0x111, 0xf>(x);   // row_shr:1
    x += dpp0<0x112, 0xf>(x);   // row_shr:2
    x += dpp0<0x114, 0xf>(x);   // row_shr:4
    x += dpp0<0x118, 0xf>(x);   // row_shr:8
    x += dpp0<0x142, 0xa>(x);   // row_bcast:15 -> rows 1,3
    x += dpp0<0x143, 0xc>(x);   // row_bcast:31 -> rows 2,3
    return bcast63(x);
}
__device__ __forceinline__ float wmin(float x) {
    const float I = 1e30f;
    x = fminf(x, dppI<0x111, 0xf>(x, I));
    x = fminf(x, dppI<0x112, 0xf>(x, I));
    x = fminf(x, dppI<0x114, 0xf>(x, I));
    x = fminf(x, dppI<0x118, 0xf>(x, I));
    x = fminf(x, dppI<0x142, 0xa>(x, I));
    x = fminf(x, dppI<0x143, 0xc>(x, I));
    return bcast63(x);
}
__device__ __forceinline__ float wmax(float x) {
    const float I = -1e30f;
    x = fmaxf(x, dppI<0x111, 0xf>(x, I));
    x = fmaxf(x, dppI<0x112, 0xf>(x, I));
    x = fmaxf(x, dppI<0x114, 0xf>(x, I));
    x = fmaxf(x, dppI<0x118, 0xf>(x, I));
    x = fmaxf(x, dppI<0x142, 0xa>(x, I));
    x = fmaxf(x, dppI<0x143, 0xc>(x, I));
    return bcast63(x);
}

__global__ void __launch_bounds__(512, 2)
markowitz_fista(const float* __restrict__ A, float* __restrict__ out)
{
    __shared__ float A_lds[32 * 256];   // build-phase A staging (32 KB)
    __shared__ float y_lds[256];        // published y / u vector
    __shared__ float p_lds[8 * 256];    // matvec partials, [e][r] layout
    __shared__ int   done_flag;

    const int tid = threadIdx.x;
    const int b   = blockIdx.x;
    const int r4  = tid & 63;
    const int e   = tid >> 6;           // wave id == col-chunk
    const int R0  = r4 * 4;
    const int C0  = e * 32;

    const float* __restrict__ Ab = A + (size_t)b * NA * NA;

    // ---------------- Phase 1: Q = A^T A into registers (packed fp32) -------
    v2f q2[4][16];
    #pragma unroll
    for (int a = 0; a < 4; ++a)
        #pragma unroll
        for (int k = 0; k < 16; ++k) q2[a][k] = (v2f){0.0f, 0.0f};

    for (int it = 0; it < 8; ++it) {
        __syncthreads();
        const float4* src = (const float4*)(Ab + it * 32 * 256);
        float4* dst = (float4*)A_lds;
        #pragma unroll
        for (int qd = 0; qd < 4; ++qd) dst[qd * 512 + tid] = src[qd * 512 + tid];
        __syncthreads();
        for (int ii = 0; ii < 32; ++ii) {
            const float* row = A_lds + ii * 256;
            float4 rv = *(const float4*)(row + R0);
            v2f r0 = {rv.x, rv.x}, r1 = {rv.y, rv.y}, r2 = {rv.z, rv.z}, r3 = {rv.w, rv.w};
            #pragma unroll
            for (int cc = 0; cc < 8; ++cc) {
                float4 cv = *(const float4*)(row + C0 + 4 * cc);
                v2f clo = {cv.x, cv.y}, chi = {cv.z, cv.w};
                q2[0][2*cc  ] = __builtin_elementwise_fma(r0, clo, q2[0][2*cc  ]);
                q2[0][2*cc+1] = __builtin_elementwise_fma(r0, chi, q2[0][2*cc+1]);
                q2[1][2*cc  ] = __builtin_elementwise_fma(r1, clo, q2[1][2*cc  ]);
                q2[1][2*cc+1] = __builtin_elementwise_fma(r1, chi, q2[1][2*cc+1]);
                q2[2][2*cc  ] = __builtin_elementwise_fma(r2, clo, q2[2][2*cc  ]);
                q2[2][2*cc+1] = __builtin_elementwise_fma(r2, chi, q2[2][2*cc+1]);
                q2[3][2*cc  ] = __builtin_elementwise_fma(r3, clo, q2[3][2*cc  ]);
                q2[3][2*cc+1] = __builtin_elementwise_fma(r3, chi, q2[3][2*cc+1]);
            }
        }
    }

    // all waves: partials of Q*y_lds into p_lds.  Returns true on early-exit
    // (flag read is issued first and hidden behind the matvec FMAs).
    auto partials = [&](bool chk) -> bool {
        __syncthreads();                               // B1: y_lds / flag visible
        int fl = chk ? done_flag : 0;
        v2f aL0 = {0,0}, aL1 = {0,0}, aL2 = {0,0}, aL3 = {0,0};
        v2f aH0 = {0,0}, aH1 = {0,0}, aH2 = {0,0}, aH3 = {0,0};
        const float* yv = y_lds + C0;
        #pragma unroll
        for (int cc = 0; cc < 8; ++cc) {
            float4 y4 = *(const float4*)(yv + 4 * cc);
            v2f ylo = {y4.x, y4.y}, yhi = {y4.z, y4.w};
            aL0 = __builtin_elementwise_fma(q2[0][2*cc  ], ylo, aL0);
            aH0 = __builtin_elementwise_fma(q2[0][2*cc+1], yhi, aH0);
            aL1 = __builtin_elementwise_fma(q2[1][2*cc  ], ylo, aL1);
            aH1 = __builtin_elementwise_fma(q2[1][2*cc+1], yhi, aH1);
            aL2 = __builtin_elementwise_fma(q2[2][2*cc  ], ylo, aL2);
            aH2 = __builtin_elementwise_fma(q2[2][2*cc+1], yhi, aH2);
            aL3 = __builtin_elementwise_fma(q2[3][2*cc  ], ylo, aL3);
            aH3 = __builtin_elementwise_fma(q2[3][2*cc+1], yhi, aH3);
        }
        if (fl) return true;                           // block-uniform
        v2f s0 = aL0 + aH0, s1 = aL1 + aH1, s2 = aL2 + aH2, s3 = aL3 + aH3;
        *(float4*)(p_lds + e * 256 + R0) =
            make_float4(s0.x + s0.y, s1.x + s1.y, s2.x + s2.y, s3.x + s3.y);
        __syncthreads();                               // B2: p_lds visible
        return false;
    };
    // wave0 (tid<64): reduce the 8 partials for rows 4*tid..4*tid+3
    auto reduceg = [&]() -> float4 {
        float4 r = *(const float4*)(p_lds + 4 * tid);
        #pragma unroll
        for (int ee = 1; ee < 8; ++ee) {
            float4 pv = *(const float4*)(p_lds + ee * 256 + 4 * tid);
            r.x += pv.x; r.y += pv.y; r.z += pv.z; r.w += pv.w;
        }
        return r;
    };

    // ---------------- Phase 2: power iteration for step size ----------------
    if (tid < 64) {
        *(float4*)(y_lds + 4 * tid) = make_float4(0.0625f, 0.0625f, 0.0625f, 0.0625f);
    }
    float u0 = 0.f, u1 = 0.f, u2 = 0.f, u3 = 0.f;
    for (int p = 0; p < 30; ++p) {
        partials(false);
        if (tid < 64) {
            float4 g4 = reduceg();
            float ss = wsum(g4.x*g4.x + g4.y*g4.y + g4.z*g4.z + g4.w*g4.w);
            float inv = 1.0f / (sqrtf(ss) + 1e-12f);
            u0 = g4.x * inv; u1 = g4.y * inv; u2 = g4.z * inv; u3 = g4.w * inv;
            *(float4*)(y_lds + 4 * tid) = make_float4(u0, u1, u2, u3);
        }
    }
    partials(false);   // Q*u for Rayleigh quotient

    float step2 = 0.f, t = 1.0f, tau_ws = 0.0f, rm = 0.0f;
    float wa = 0.f, wb = 0.f, wc = 0.f, wd = 0.f;
    float ya = 0.f, yb = 0.f, yc = 0.f, yd = 0.f;
    if (tid < 64) {
        float4 g4 = reduceg();
        float lm = wsum(u0*g4.x + u1*g4.y + u2*g4.z + u3*g4.w);
        float step = 1.0f / (2.0f * lm + 1e-12f);
        step2 = 2.0f * step;
        wa = wb = wc = wd = 1.0f / 256.0f;    // project(uniform) = uniform (tau=0)
        ya = yb = yc = yd = 1.0f / 256.0f;
        *(float4*)(y_lds + 4 * tid) = make_float4(ya, yb, yc, yd);
    }
    if (tid == 0) done_flag = 0;               // ordered by next B1

    // ---------------- Phase 3: FISTA ----------------
    for (int itn = 0; itn < 300; ++itn) {
        if (partials(true)) break;             // frozen-w early exit (uniform)
        if (tid < 64) {
            float4 g4 = reduceg();
            float v0 = ya - step2 * g4.x;
            float v1 = yb - step2 * g4.y;
            float v2 = yc - step2 * g4.z;
            float v3 = yd - step2 * g4.w;

            float lo = wmin(fminf(fminf(v0, v1), fminf(v2, v3))) - CAPW;
            float hi = wmax(fmaxf(fmaxf(v0, v1), fmaxf(v2, v3))) + CAPW;
            float tau = fminf(fmaxf(tau_ws, lo), hi);

            float s = 0.f, cnt = 1.f, sm1 = 0.f;
            bool have = false;
            for (int ni = 0; ni < 10; ++ni) {
                float z0 = v0 - tau, z1 = v1 - tau, z2 = v2 - tau, z3 = v3 - tau;
                float c0 = fminf(fmaxf(z0, -CAPW), CAPW);
                float c1 = fminf(fmaxf(z1, -CAPW), CAPW);
                float c2 = fminf(fmaxf(z2, -CAPW), CAPW);
                float c3 = fminf(fmaxf(z3, -CAPW), CAPW);
                s   = wsum(c0 + c1 + c2 + c3);
                cnt = wsum((fabsf(z0) < CAPW ? 1.f : 0.f) +
                           (fabsf(z1) < CAPW ? 1.f : 0.f) +
                           (fabsf(z2) < CAPW ? 1.f : 0.f) +
                           (fabsf(z3) < CAPW ? 1.f : 0.f));
                sm1 = s - 1.0f;
                if (fabsf(sm1) <= 1e-5f) { have = true; break; }   // wave-uniform
                if (sm1 > 0.0f) lo = tau; else hi = tau;
                float tn2 = tau + sm1 / fmaxf(cnt, 1.0f);   // Newton: s' = -n_int
                if (!(tn2 > lo && tn2 < hi)) tn2 = 0.5f * (lo + hi);
                tau = tn2;
            }
            if (!have) {   // bound-exit: re-eval (s,cnt) at final tau
                float z0 = v0 - tau, z1 = v1 - tau, z2 = v2 - tau, z3 = v3 - tau;
                float c0 = fminf(fmaxf(z0, -CAPW), CAPW);
                float c1 = fminf(fmaxf(z1, -CAPW), CAPW);
                float c2 = fminf(fmaxf(z2, -CAPW), CAPW);
                float c3 = fminf(fmaxf(z3, -CAPW), CAPW);
                s   = wsum(c0 + c1 + c2 + c3);
                cnt = wsum((fabsf(z0) < CAPW ? 1.f : 0.f) +
                           (fabsf(z1) < CAPW ? 1.f : 0.f) +
                           (fabsf(z2) < CAPW ? 1.f : 0.f) +
                           (fabsf(z3) < CAPW ? 1.f : 0.f));
                sm1 = s - 1.0f;
            }
            // exact active-set tau == one Newton step from converged point
            float tauf = tau + sm1 / fmaxf(cnt, 1.0f);
            tau_ws = tauf;
            float w0n = fminf(fmaxf(v0 - tauf, -CAPW), CAPW);
            float w1n = fminf(fmaxf(v1 - tauf, -CAPW), CAPW);
            float w2n = fminf(fmaxf(v2 - tauf, -CAPW), CAPW);
            float w3n = fminf(fmaxf(v3 - tauf, -CAPW), CAPW);

            float tn = 0.5f * (1.0f + sqrtf(1.0f + 4.0f * t * t));
            float beta = (t - 1.0f) / tn;
            float y0n = w0n + beta * (w0n - wa);
            float y1n = w1n + beta * (w1n - wb);
            float y2n = w2n + beta * (w2n - wc);
            float y3n = w3n + beta * (w3n - wd);

            // frozen-w detection (8-iter window, fp32 fixed point only)
            float dm = fmaxf(fmaxf(fabsf(w0n - wa), fabsf(w1n - wb)),
                             fmaxf(fabsf(w2n - wc), fabsf(w3n - wd)));
            rm = fmaxf(rm, dm);
            if ((itn & 7) == 7) {
                float rmax = wmax(rm);
                if (rmax < 1e-10f && tid == 0) done_flag = 1;
                rm = 0.0f;
            }

            wa = w0n; wb = w1n; wc = w2n; wd = w3n;
            ya = y0n; yb = y1n; yc = y2n; yd = y3n;
            t = tn;
            *(float4*)(y_lds + 4 * tid) = make_float4(ya, yb, yc, yd);
        }
    }

    if (tid < 64) {
        *(float4*)(out + b * 256 + 4 * tid) = make_float4(wa, wb, wc, wd);
    }
}

extern "C" void kernel_launch(void* const* d_in, const int* in_sizes, int n_in,
                              void* d_out, int out_size, void* d_ws, size_t ws_size,
                              hipStream_t stream) {
    (void)in_sizes; (void)n_in; (void)d_ws; (void)ws_size; (void)out_size;
    const float* A = (const float*)d_in[0];
    float* out = (float*)d_out;
    hipLaunchKernelGGL(markowitz_fista, dim3(512), dim3(512), 0, stream, A, out);
}